// Round 14
// baseline (512.215 us; speedup 1.0000x reference)
//
#include <hip/hip_runtime.h>

#define HIDDEN 128
#define N_RAYS 65536
#define NEAR_D 0.01f
#define FAR_D 10.0f
#define MAX_ITERS 32

typedef _Float16 f16x8 __attribute__((ext_vector_type(8)));
typedef _Float16 f16x2 __attribute__((ext_vector_type(2)));
typedef __fp16   h16x2 __attribute__((ext_vector_type(2)));   // cvt_pkrtz result type
typedef float f32x16 __attribute__((ext_vector_type(16)));
typedef float v2f __attribute__((ext_vector_type(2)));

__device__ __forceinline__ v2f fma2(v2f a, v2f b, v2f c) {
    return __builtin_elementwise_fma(a, b, c);
}

// pkrtz wrapper returning our f16x2 (bit-identical layouts; union converts)
__device__ __forceinline__ f16x2 pkrtz(float a, float b) {
    union { h16x2 h; f16x2 f; } u;
    u.h = __builtin_amdgcn_cvt_pkrtz(a, b);
    return u.f;
}

// DPP-assisted add: v + (v shifted by CTRL). bound_ctrl=1 -> OOB lanes give 0.
template <int CTRL, int ROW_MASK>
__device__ __forceinline__ float dpp_add(float v) {
    int s = __builtin_amdgcn_update_dpp(0, __float_as_int(v), CTRL, ROW_MASK, 0xF, true);
    return v + __int_as_float(s);
}
// Sum over each 32-lane half; result lands in lane 31 (half 0) / lane 63 (half 1).
__device__ __forceinline__ float half_sum_dpp(float v) {
    v = dpp_add<0x111, 0xF>(v);   // row_shr:1
    v = dpp_add<0x112, 0xF>(v);   // row_shr:2
    v = dpp_add<0x114, 0xF>(v);   // row_shr:4
    v = dpp_add<0x118, 0xF>(v);   // row_shr:8
    v = dpp_add<0x142, 0xA>(v);   // row_bcast15 -> lanes 31/63 hold 32-sums
    return v;
}

// ---------------------------------------------------------------------------
// Prologue: W2 B-operand fragment image (fp16 hi | lo) + pair-SoA W1 quads.
//   img[l*16384 + (t*8+c)*512 + L*8 + j] == limb_l( W2[k][n] ),
//   n = t*32 + (L&31),  k = c*16 + ((L>>5)&1)*8 + j.
//   w1q[2p]   = {wx[2p], wx[2p+1], wy[2p], wy[2p+1]}
//   w1q[2p+1] = {wz[2p], wz[2p+1], b1[2p], b1[2p+1]}   (pair-SoA for pk math)
// ---------------------------------------------------------------------------
__global__ void w2_frag_kernel(const float* __restrict__ W2,
                               const float* __restrict__ W1,
                               const float* __restrict__ b1,
                               _Float16* __restrict__ img,
                               float4* __restrict__ w1q) {
    int tid = blockIdx.x * blockDim.x + threadIdx.x;   // 0..16383
    if (blockIdx.x == 0 && threadIdx.x < 64) {
        const int p = threadIdx.x;
        const int k0 = 2 * p, k1 = 2 * p + 1;
        float4 a, b;
        a.x = W1[k0];              a.y = W1[k1];
        a.z = W1[HIDDEN + k0];     a.w = W1[HIDDEN + k1];
        b.x = W1[2 * HIDDEN + k0]; b.y = W1[2 * HIDDEN + k1];
        b.z = b1[k0];              b.w = b1[k1];
        w1q[2 * p]     = a;
        w1q[2 * p + 1] = b;
    }
    int j = tid & 7;
    int L = (tid >> 3) & 63;
    int tc = tid >> 9;
    int t = tc >> 3, c = tc & 7;
    int n = t * 32 + (L & 31);
    int k = c * 16 + ((L >> 5) & 1) * 8 + j;
    float w = W2[k * HIDDEN + n];
    _Float16 hi = (_Float16)w;
    _Float16 lo = (_Float16)(w - (float)hi);
    img[tid] = hi;
    img[16384 + tid] = lo;
}

// ---------------------------------------------------------------------------
// Block = 256 threads = 4 independent waves, 32 rays/wave, MFMA layer-2.
// R14 = R13 with the cvt_pkrtz type fixed: (1) layer-1 + f16 limb split on
// packed fp32 pipes (pk_fma/pk_max/pk_mul + cvt_pkrtz), (2) pk epilogue,
// (3) fully-unrolled chunk loop with sched_barrier(0) fences -> all LDS/w1q
// offsets immediate, live ranges pinned chunk-local (anti-spill guard).
// ---------------------------------------------------------------------------
__launch_bounds__(256, 2)
__global__ void sphere_trace_kernel(
    const float* __restrict__ origins,
    const float* __restrict__ directions,
    const float* __restrict__ W1,    // [3][128] (wave-setup bounds only)
    const float* __restrict__ b1,    // [128]    (wave-setup bounds only)
    const float4* __restrict__ w1q,  // [128] pair-SoA quads
    const _Float16* __restrict__ w2img, // 32768 halfs (hi | lo)
    const float* __restrict__ b2,    // [128]
    const float* __restrict__ W3,    // [128]
    const float* __restrict__ b3,    // [1]
    const float* __restrict__ Wc1,   // [3][128]
    const float* __restrict__ bc1,   // [128]
    const float* __restrict__ Wc2,   // [128][3]
    const float* __restrict__ bc2,   // [3]
    float* __restrict__ out)         // [N][3]
{
    __shared__ __align__(16) _Float16 wlds[32768];   // 64 KB fragment image
    __shared__ float sbuf[4][32];                    // per-wave s exchange

    const int tid = threadIdx.x;
    const int lane = tid & 63;
    const int w = __builtin_amdgcn_readfirstlane(tid >> 6);
    const int q = lane >> 5;           // half-wave id
    const int n32 = lane & 31;         // N-column within tile / ray id

    // ---- stage fragment image into LDS (only __syncthreads in the kernel)
    {
        const float4* src = (const float4*)w2img;
        float4* dst = (float4*)wlds;
        #pragma unroll
        for (int i = 0; i < 16; ++i)
            dst[tid + 256 * i] = src[tid + 256 * i];
    }
    __syncthreads();

    // ---- analytic layer-1 magnitude bound constants (once per wave)
    float bAx, bAy, bAz, bB;
    {
        bAx = fmaxf(fabsf(W1[lane]),              fabsf(W1[lane + 64]));
        bAy = fmaxf(fabsf(W1[HIDDEN + lane]),     fabsf(W1[HIDDEN + lane + 64]));
        bAz = fmaxf(fabsf(W1[2 * HIDDEN + lane]), fabsf(W1[2 * HIDDEN + lane + 64]));
        bB  = fmaxf(fabsf(b1[lane]),              fabsf(b1[lane + 64]));
        #pragma unroll
        for (int m = 1; m < 64; m <<= 1) {
            bAx = fmaxf(bAx, __shfl_xor(bAx, m));
            bAy = fmaxf(bAy, __shfl_xor(bAy, m));
            bAz = fmaxf(bAz, __shfl_xor(bAz, m));
            bB  = fmaxf(bB,  __shfl_xor(bB,  m));
        }
    }

    // ---- ray state (owner lanes 0..31)
    const int ray = blockIdx.x * 128 + w * 32 + n32;
    float px = 0.f, py = 0.f, pz = 0.f, dx = 0.f, dy = 0.f, dz = 0.f;
    float dist = 0.0f;
    bool frozen = true;
    if (lane < 32) {
        px = origins[ray * 3 + 0];
        py = origins[ray * 3 + 1];
        pz = origins[ray * 3 + 2];
        dx = directions[ray * 3 + 0];
        dy = directions[ray * 3 + 1];
        dz = directions[ray * 3 + 2];
        frozen = false;
    }

    // ---- per-lane epilogue constants (4 output columns n = t*32 + n32)
    float b2v[4], w3v[4];
    #pragma unroll
    for (int t = 0; t < 4; ++t) {
        b2v[t] = b2[t * 32 + n32];
        w3v[t] = W3[t * 32 + n32];
    }
    const float b3v = b3[0];

    // hoisted bases (immediate offsets hang off these)
    const float4* __restrict__ wq = w1q + (q << 3);        // half-wave's pair set
    const _Float16* __restrict__ wbase = wlds + (lane << 3);

    #pragma unroll 1
    for (int it = 0; it < MAX_ITERS; ++it) {
        // broadcast ray n32's position to all lanes
        const float ppx = __shfl(px, n32);
        const float ppy = __shfl(py, n32);
        const float ppz = __shfl(pz, n32);

        // ---- analytic pow2 scale (bound >= true max of h for this ray)
        const float bound = fmaf(fabsf(ppx), bAx, fmaf(fabsf(ppy), bAy,
                            fmaf(fabsf(ppz), bAz, bB)));
        float sc = 1.0f, inv = 1.0f;
        {
            const int e = (int)((__float_as_uint(bound) >> 23) & 255u);
            if (e > 137) {
                const int sh = e - 137;
                sc  = __uint_as_float((unsigned)(127 - sh) << 23);
                inv = __uint_as_float((unsigned)(127 + sh) << 23);
            }
        }
        v2f px2; px2.x = ppx; px2.y = ppx;
        v2f py2; py2.x = ppy; py2.y = ppy;
        v2f pz2; pz2.x = ppz; pz2.y = ppz;
        v2f sc2; sc2.x = sc;  sc2.y = sc;
        v2f zero2; zero2.x = 0.f; zero2.y = 0.f;

        // ---- layer 2: fully-unrolled chunk loop, pk A-build, fenced per chunk
        f32x16 acc[4];
        #pragma unroll
        for (int t = 0; t < 4; ++t)
            #pragma unroll
            for (int r = 0; r < 16; ++r) acc[t][r] = 0.0f;

        #pragma unroll
        for (int c = 0; c < 8; ++c) {
            union { f16x2 p[4]; f16x8 v; } ah, al;
            #pragma unroll
            for (int i = 0; i < 4; ++i) {
                const float4 fa = wq[16 * c + 2 * i];
                const float4 fb = wq[16 * c + 2 * i + 1];
                v2f wx; wx.x = fa.x; wx.y = fa.y;
                v2f wy; wy.x = fa.z; wy.y = fa.w;
                v2f wz; wz.x = fb.x; wz.y = fb.y;
                v2f wb; wb.x = fb.z; wb.y = fb.w;
                v2f a = fma2(px2, wx, fma2(py2, wy, fma2(pz2, wz, wb)));
                a = __builtin_elementwise_max(a, zero2);   // relu (pk_max)
                a = a * sc2;                               // exact pow2 (pk_mul)
                const f16x2 hi = pkrtz(a.x, a.y);
                v2f hiF; hiF.x = (float)hi.x; hiF.y = (float)hi.y;
                const v2f lo = a - hiF;                    // exact residual
                ah.p[i] = hi;
                al.p[i] = pkrtz(lo.x, lo.y);
            }
            const f16x8 Ah = ah.v;
            const f16x8 Al = al.v;
            #pragma unroll
            for (int t = 0; t < 4; ++t) {
                const f16x8 bh = *(const f16x8*)(wbase + ((t * 8 + c) << 9));
                const f16x8 bl = *(const f16x8*)(wbase + 16384 + ((t * 8 + c) << 9));
                acc[t] = __builtin_amdgcn_mfma_f32_32x32x16_f16(Ah, bh, acc[t], 0, 0, 0);
                acc[t] = __builtin_amdgcn_mfma_f32_32x32x16_f16(Ah, bl, acc[t], 0, 0, 0);
                acc[t] = __builtin_amdgcn_mfma_f32_32x32x16_f16(Al, bh, acc[t], 0, 0, 0);
            }
            __builtin_amdgcn_sched_barrier(0);   // pin live ranges chunk-local
        }

        // ---- epilogue: pk relu/dot; DPP reduction
        float invr[16];
        #pragma unroll
        for (int r = 0; r < 16; ++r) {
            const int msrc = (r & 3) + 8 * (r >> 2) + 4 * q;
            invr[r] = __shfl(inv, msrc);
        }
        v2f invp[8], psp[8];
        #pragma unroll
        for (int r2 = 0; r2 < 8; ++r2) {
            invp[r2].x = invr[2 * r2]; invp[r2].y = invr[2 * r2 + 1];
            psp[r2].x = 0.f; psp[r2].y = 0.f;
        }
        #pragma unroll
        for (int t = 0; t < 4; ++t) {
            v2f b2s; b2s.x = b2v[t]; b2s.y = b2v[t];
            v2f w3s; w3s.x = w3v[t]; w3s.y = w3v[t];
            #pragma unroll
            for (int r2 = 0; r2 < 8; ++r2) {
                v2f accp; accp.x = acc[t][2 * r2]; accp.y = acc[t][2 * r2 + 1];
                v2f v = fma2(accp, invp[r2], b2s);
                v = __builtin_elementwise_max(v, zero2);
                psp[r2] = fma2(v, w3s, psp[r2]);
            }
        }
        float ps[16];
        #pragma unroll
        for (int r2 = 0; r2 < 8; ++r2) {
            ps[2 * r2]     = half_sum_dpp(psp[r2].x);
            ps[2 * r2 + 1] = half_sum_dpp(psp[r2].y);
        }
        if ((lane & 31) == 31) {
            const int mb = q * 4;
            #pragma unroll
            for (int g = 0; g < 4; ++g) {
                float4 v4;
                v4.x = ps[4 * g + 0];
                v4.y = ps[4 * g + 1];
                v4.z = ps[4 * g + 2];
                v4.w = ps[4 * g + 3];
                *(float4*)&sbuf[w][8 * g + mb] = v4;
            }
        }
        float s = 0.0f;
        if (lane < 32) s = sbuf[w][lane] + b3v;

        // ---- march (exact reference semantics) on owner lanes
        if (lane < 32) {
            const bool valid = (s <= NEAR_D) && (dist < FAR_D);
            if (!frozen) {
                if (valid) {
                    frozen = true;
                } else {
                    dist += s;
                    px = fmaf(dx, s, px);
                    py = fmaf(dy, s, py);
                    pz = fmaf(dz, s, pz);
                }
            }
        }
        if (__ballot((lane < 32) && !frozen) == 0) break;
    }

    // ---- color MLP (once): lane owns hidden units lane, lane+64
    const int k0 = lane, k1 = lane + 64;
    const float cx0 = Wc1[k0], cx1 = Wc1[k1];
    const float cy0 = Wc1[HIDDEN + k0], cy1 = Wc1[HIDDEN + k1];
    const float cz0 = Wc1[2 * HIDDEN + k0], cz1 = Wc1[2 * HIDDEN + k1];
    const float cb0 = bc1[k0], cb1 = bc1[k1];
    const float u00 = Wc2[k0 * 3 + 0], u01 = Wc2[k0 * 3 + 1], u02 = Wc2[k0 * 3 + 2];
    const float u10 = Wc2[k1 * 3 + 0], u11 = Wc2[k1 * 3 + 1], u12 = Wc2[k1 * 3 + 2];

    float g0 = 0.f, g1 = 0.f, g2 = 0.f;
    #pragma unroll 1
    for (int m = 0; m < 32; ++m) {
        const float qx = __shfl(px, m);
        const float qy = __shfl(py, m);
        const float qz = __shfl(pz, m);
        const float h0 = fmaxf(fmaf(qx, cx0, fmaf(qy, cy0, fmaf(qz, cz0, cb0))), 0.f);
        const float h1 = fmaxf(fmaf(qx, cx1, fmaf(qy, cy1, fmaf(qz, cz1, cb1))), 0.f);
        float a0 = fmaf(h0, u00, h1 * u10);
        float a1 = fmaf(h0, u01, h1 * u11);
        float a2 = fmaf(h0, u02, h1 * u12);
        #pragma unroll
        for (int mask = 1; mask < 64; mask <<= 1) {
            a0 += __shfl_xor(a0, mask);
            a1 += __shfl_xor(a1, mask);
            a2 += __shfl_xor(a2, mask);
        }
        if (lane == m) { g0 = a0; g1 = a1; g2 = a2; }
    }

    if (lane < 32) {
        float c0 = 0.f, c1 = 0.f, c2 = 0.f;
        if (frozen || dist < FAR_D) {
            c0 = 1.0f / (1.0f + __expf(-(g0 + bc2[0])));
            c1 = 1.0f / (1.0f + __expf(-(g1 + bc2[1])));
            c2 = 1.0f / (1.0f + __expf(-(g2 + bc2[2])));
        }
        out[ray * 3 + 0] = c0;
        out[ray * 3 + 1] = c1;
        out[ray * 3 + 2] = c2;
    }
}

extern "C" void kernel_launch(void* const* d_in, const int* in_sizes, int n_in,
                              void* d_out, int out_size, void* d_ws, size_t ws_size,
                              hipStream_t stream) {
    const float* origins    = (const float*)d_in[0];
    const float* directions = (const float*)d_in[1];
    const float* W1  = (const float*)d_in[2];
    const float* b1  = (const float*)d_in[3];
    const float* W2  = (const float*)d_in[4];
    const float* b2  = (const float*)d_in[5];
    const float* W3  = (const float*)d_in[6];
    const float* b3  = (const float*)d_in[7];
    const float* Wc1 = (const float*)d_in[8];
    const float* bc1 = (const float*)d_in[9];
    const float* Wc2 = (const float*)d_in[10];
    const float* bc2 = (const float*)d_in[11];
    float* out = (float*)d_out;

    char* ws = (char*)d_ws;
    _Float16* w2img = (_Float16*)ws;            // 64 KB
    float4*   w1q   = (float4*)(ws + 65536);    // 2 KB, 16B-aligned

    w2_frag_kernel<<<64, 256, 0, stream>>>(W2, W1, b1, w2img, w1q);

    sphere_trace_kernel<<<N_RAYS / 128, 256, 0, stream>>>(
        origins, directions, W1, b1, w1q, w2img, b2, W3, b3,
        Wc1, bc1, Wc2, bc2, out);
}

// Round 15
// 401.062 us; speedup vs baseline: 1.2771x; 1.2771x over previous
//
#include <hip/hip_runtime.h>

#define HIDDEN 128
#define N_RAYS 65536
#define NEAR_D 0.01f
#define FAR_D 10.0f
#define MAX_ITERS 32

typedef _Float16 f16x8 __attribute__((ext_vector_type(8)));
typedef _Float16 f16x2 __attribute__((ext_vector_type(2)));
typedef __fp16   h16x2 __attribute__((ext_vector_type(2)));
typedef float f32x16 __attribute__((ext_vector_type(16)));
typedef float v2f __attribute__((ext_vector_type(2)));

__device__ __forceinline__ v2f fma2(v2f a, v2f b, v2f c) {
    return __builtin_elementwise_fma(a, b, c);
}
__device__ __forceinline__ f16x2 pkrtz(float a, float b) {
    union { h16x2 h; f16x2 f; } u;
    u.h = __builtin_amdgcn_cvt_pkrtz(a, b);
    return u.f;
}
template <int CTRL, int ROW_MASK>
__device__ __forceinline__ float dpp_add(float v) {
    int s = __builtin_amdgcn_update_dpp(0, __float_as_int(v), CTRL, ROW_MASK, 0xF, true);
    return v + __int_as_float(s);
}
// Sum over each 32-lane half; result lands in lane 31 (half 0) / lane 63 (half 1).
__device__ __forceinline__ float half_sum_dpp(float v) {
    v = dpp_add<0x111, 0xF>(v);
    v = dpp_add<0x112, 0xF>(v);
    v = dpp_add<0x114, 0xF>(v);
    v = dpp_add<0x118, 0xF>(v);
    v = dpp_add<0x142, 0xA>(v);
    return v;
}

// ---------------------------------------------------------------------------
// Prologue: W2 B-operand fragment image (fp16 hi | lo) + pair-SoA W1 quads.
//   img[l*16384 + (t*8+c)*512 + L*8 + j] == limb_l( W2[k][n] ),
//   n = t*32 + (L&31),  k = c*16 + ((L>>5)&1)*8 + j.
// ---------------------------------------------------------------------------
__global__ void w2_frag_kernel(const float* __restrict__ W2,
                               const float* __restrict__ W1,
                               const float* __restrict__ b1,
                               _Float16* __restrict__ img,
                               float4* __restrict__ w1q) {
    int tid = blockIdx.x * blockDim.x + threadIdx.x;   // 0..16383
    if (blockIdx.x == 0 && threadIdx.x < 64) {
        const int p = threadIdx.x;
        const int k0 = 2 * p, k1 = 2 * p + 1;
        float4 a, b;
        a.x = W1[k0];              a.y = W1[k1];
        a.z = W1[HIDDEN + k0];     a.w = W1[HIDDEN + k1];
        b.x = W1[2 * HIDDEN + k0]; b.y = W1[2 * HIDDEN + k1];
        b.z = b1[k0];              b.w = b1[k1];
        w1q[2 * p]     = a;
        w1q[2 * p + 1] = b;
    }
    int j = tid & 7;
    int L = (tid >> 3) & 63;
    int tc = tid >> 9;
    int t = tc >> 3, c = tc & 7;
    int n = t * 32 + (L & 31);
    int k = c * 16 + ((L >> 5) & 1) * 8 + j;
    float w = W2[k * HIDDEN + n];
    _Float16 hi = (_Float16)w;
    _Float16 lo = (_Float16)(w - (float)hi);
    img[tid] = hi;
    img[16384 + tid] = lo;
}

// ---------------------------------------------------------------------------
// R15: 512-thread blocks = 8 waves sharing ONE 64 KB W2 image -> 16 waves/CU
// (4/SIMD) at the same total DS traffic. Wave pair (pair, e) duplicates ray
// state for 32 rays; wave e computes N-tiles {2e,2e+1} (acc[2], 32 AGPRs).
// Layer-3 partials exchanged via double-buffered LDS + ONE barrier/iter.
// Finished pairs skip heavy work but keep hitting the barrier. Chunk loop
// stays `#pragma unroll 1` (full unroll spilled in R9/R14 — locked rule).
// A-build = R14's validated pk path (absmax 3e-5).
// ---------------------------------------------------------------------------
__launch_bounds__(512, 4)
__global__ void sphere_trace_kernel(
    const float* __restrict__ origins,
    const float* __restrict__ directions,
    const float* __restrict__ W1,    // [3][128] (wave-setup bounds only)
    const float* __restrict__ b1,    // [128]    (wave-setup bounds only)
    const float4* __restrict__ w1q,  // [128] pair-SoA quads
    const _Float16* __restrict__ w2img, // 32768 halfs (hi | lo)
    const float* __restrict__ b2,    // [128]
    const float* __restrict__ W3,    // [128]
    const float* __restrict__ b3,    // [1]
    const float* __restrict__ Wc1,   // [3][128]
    const float* __restrict__ bc1,   // [128]
    const float* __restrict__ Wc2,   // [128][3]
    const float* __restrict__ bc2,   // [3]
    float* __restrict__ out)         // [N][3]
{
    __shared__ __align__(16) _Float16 wlds[32768];   // 64 KB fragment image
    __shared__ float sbuf[2][4][2][32];              // dbuf: [parity][pair][e][ray]
    __shared__ __align__(16) int flags[2][4];        // dbuf: pair-active flags

    const int tid = threadIdx.x;
    const int lane = tid & 63;
    const int w = __builtin_amdgcn_readfirstlane(tid >> 6);  // 0..7
    const int pair = w >> 1;
    const int e = w & 1;
    const int q = lane >> 5;
    const int n32 = lane & 31;

    // ---- stage fragment image into LDS
    {
        const float4* src = (const float4*)w2img;
        float4* dst = (float4*)wlds;
        #pragma unroll
        for (int i = 0; i < 8; ++i)
            dst[tid + 512 * i] = src[tid + 512 * i];
    }
    __syncthreads();

    // ---- analytic layer-1 magnitude bound constants (once per wave)
    float bAx, bAy, bAz, bB;
    {
        bAx = fmaxf(fabsf(W1[lane]),              fabsf(W1[lane + 64]));
        bAy = fmaxf(fabsf(W1[HIDDEN + lane]),     fabsf(W1[HIDDEN + lane + 64]));
        bAz = fmaxf(fabsf(W1[2 * HIDDEN + lane]), fabsf(W1[2 * HIDDEN + lane + 64]));
        bB  = fmaxf(fabsf(b1[lane]),              fabsf(b1[lane + 64]));
        #pragma unroll
        for (int m = 1; m < 64; m <<= 1) {
            bAx = fmaxf(bAx, __shfl_xor(bAx, m));
            bAy = fmaxf(bAy, __shfl_xor(bAy, m));
            bAz = fmaxf(bAz, __shfl_xor(bAz, m));
            bB  = fmaxf(bB,  __shfl_xor(bB,  m));
        }
    }

    // ---- ray state (owner lanes 0..31; DUPLICATED in both waves of a pair)
    const int ray = blockIdx.x * 128 + pair * 32 + n32;
    float px = 0.f, py = 0.f, pz = 0.f, dx = 0.f, dy = 0.f, dz = 0.f;
    float dist = 0.0f;
    bool frozen = true;
    if (lane < 32) {
        px = origins[ray * 3 + 0];
        py = origins[ray * 3 + 1];
        pz = origins[ray * 3 + 2];
        dx = directions[ray * 3 + 0];
        dy = directions[ray * 3 + 1];
        dz = directions[ray * 3 + 2];
        frozen = false;
    }

    // ---- per-lane epilogue constants: my 2 output tiles t = 2e+i
    float b2v[2], w3v[2];
    #pragma unroll
    for (int i = 0; i < 2; ++i) {
        b2v[i] = b2[e * 64 + i * 32 + n32];
        w3v[i] = W3[e * 64 + i * 32 + n32];
    }
    const float b3v = b3[0];

    // hoisted bases
    const float4* __restrict__ wq = w1q + (q << 3);
    const _Float16* __restrict__ ebase = wlds + (lane << 3) + (e << 13); // + t-major offset

    #pragma unroll 1
    for (int it = 0; it < MAX_ITERS; ++it) {
        // pair-activity (identical in both waves of the pair)
        const bool active = __ballot((lane < 32) && !frozen) != 0ull;

        if (active) {
            const float ppx = __shfl(px, n32);
            const float ppy = __shfl(py, n32);
            const float ppz = __shfl(pz, n32);

            // analytic pow2 scale
            const float bound = fmaf(fabsf(ppx), bAx, fmaf(fabsf(ppy), bAy,
                                fmaf(fabsf(ppz), bAz, bB)));
            float sc = 1.0f, inv = 1.0f;
            {
                const int ex = (int)((__float_as_uint(bound) >> 23) & 255u);
                if (ex > 137) {
                    const int sh = ex - 137;
                    sc  = __uint_as_float((unsigned)(127 - sh) << 23);
                    inv = __uint_as_float((unsigned)(127 + sh) << 23);
                }
            }
            v2f px2; px2.x = ppx; px2.y = ppx;
            v2f py2; py2.x = ppy; py2.y = ppy;
            v2f pz2; pz2.x = ppz; pz2.y = ppz;
            v2f sc2; sc2.x = sc;  sc2.y = sc;
            v2f zero2; zero2.x = 0.f; zero2.y = 0.f;

            // layer 2: chunk-outer (unroll 1), pk A-build, 2 N-tiles from LDS
            f32x16 acc[2];
            #pragma unroll
            for (int t = 0; t < 2; ++t)
                #pragma unroll
                for (int r = 0; r < 16; ++r) acc[t][r] = 0.0f;

            #pragma unroll 1
            for (int c = 0; c < 8; ++c) {
                union { f16x2 p[4]; f16x8 v; } ah, al;
                #pragma unroll
                for (int i = 0; i < 4; ++i) {
                    const float4 fa = wq[16 * c + 2 * i];
                    const float4 fb = wq[16 * c + 2 * i + 1];
                    v2f wx; wx.x = fa.x; wx.y = fa.y;
                    v2f wy; wy.x = fa.z; wy.y = fa.w;
                    v2f wz; wz.x = fb.x; wz.y = fb.y;
                    v2f wb; wb.x = fb.z; wb.y = fb.w;
                    v2f a = fma2(px2, wx, fma2(py2, wy, fma2(pz2, wz, wb)));
                    a = __builtin_elementwise_max(a, zero2);   // relu
                    a = a * sc2;                               // exact pow2
                    const f16x2 hi = pkrtz(a.x, a.y);
                    v2f hiF; hiF.x = (float)hi.x; hiF.y = (float)hi.y;
                    const v2f lo = a - hiF;                    // exact residual
                    ah.p[i] = hi;
                    al.p[i] = pkrtz(lo.x, lo.y);
                }
                const f16x8 Ah = ah.v;
                const f16x8 Al = al.v;
                #pragma unroll
                for (int i = 0; i < 2; ++i) {
                    const f16x8 bh = *(const f16x8*)(ebase + ((i * 8 + c) << 9));
                    const f16x8 bl = *(const f16x8*)(ebase + 16384 + ((i * 8 + c) << 9));
                    acc[i] = __builtin_amdgcn_mfma_f32_32x32x16_f16(Ah, bh, acc[i], 0, 0, 0);
                    acc[i] = __builtin_amdgcn_mfma_f32_32x32x16_f16(Ah, bl, acc[i], 0, 0, 0);
                    acc[i] = __builtin_amdgcn_mfma_f32_32x32x16_f16(Al, bh, acc[i], 0, 0, 0);
                }
            }

            // epilogue: pk relu/dot over my 2 tiles; DPP reduce; publish
            float invr[16];
            #pragma unroll
            for (int r = 0; r < 16; ++r) {
                const int msrc = (r & 3) + 8 * (r >> 2) + 4 * q;
                invr[r] = __shfl(inv, msrc);
            }
            v2f invp[8], psp[8];
            #pragma unroll
            for (int r2 = 0; r2 < 8; ++r2) {
                invp[r2].x = invr[2 * r2]; invp[r2].y = invr[2 * r2 + 1];
                psp[r2].x = 0.f; psp[r2].y = 0.f;
            }
            #pragma unroll
            for (int t = 0; t < 2; ++t) {
                v2f b2s; b2s.x = b2v[t]; b2s.y = b2v[t];
                v2f w3s; w3s.x = w3v[t]; w3s.y = w3v[t];
                #pragma unroll
                for (int r2 = 0; r2 < 8; ++r2) {
                    v2f accp; accp.x = acc[t][2 * r2]; accp.y = acc[t][2 * r2 + 1];
                    v2f v = fma2(accp, invp[r2], b2s);
                    v = __builtin_elementwise_max(v, zero2);
                    psp[r2] = fma2(v, w3s, psp[r2]);
                }
            }
            float ps[16];
            #pragma unroll
            for (int r2 = 0; r2 < 8; ++r2) {
                ps[2 * r2]     = half_sum_dpp(psp[r2].x);
                ps[2 * r2 + 1] = half_sum_dpp(psp[r2].y);
            }
            if ((lane & 31) == 31) {
                const int mb = q * 4;
                #pragma unroll
                for (int g = 0; g < 4; ++g) {
                    float4 v4;
                    v4.x = ps[4 * g + 0];
                    v4.y = ps[4 * g + 1];
                    v4.z = ps[4 * g + 2];
                    v4.w = ps[4 * g + 3];
                    *(float4*)&sbuf[it & 1][pair][e][8 * g + mb] = v4;
                }
            }
        }

        if (e == 0 && lane == 0) flags[it & 1][pair] = active ? 1 : 0;
        __syncthreads();   // the ONE barrier per iteration

        if (active && lane < 32) {
            const float s = sbuf[it & 1][pair][0][lane]
                          + sbuf[it & 1][pair][1][lane] + b3v;
            // march (exact reference semantics)
            const bool valid = (s <= NEAR_D) && (dist < FAR_D);
            if (!frozen) {
                if (valid) {
                    frozen = true;
                } else {
                    dist += s;
                    px = fmaf(dx, s, px);
                    py = fmaf(dy, s, py);
                    pz = fmaf(dz, s, pz);
                }
            }
        }
        // block-uniform break (double-buffered flags; safe with one barrier)
        const int4 f = *(const int4*)&flags[it & 1][0];
        if ((f.x | f.y | f.z | f.w) == 0) break;
    }

    // ---- color MLP (once): lane owns hidden units lane, lane+64
    const int k0 = lane, k1 = lane + 64;
    const float cx0 = Wc1[k0], cx1 = Wc1[k1];
    const float cy0 = Wc1[HIDDEN + k0], cy1 = Wc1[HIDDEN + k1];
    const float cz0 = Wc1[2 * HIDDEN + k0], cz1 = Wc1[2 * HIDDEN + k1];
    const float cb0 = bc1[k0], cb1 = bc1[k1];
    const float u00 = Wc2[k0 * 3 + 0], u01 = Wc2[k0 * 3 + 1], u02 = Wc2[k0 * 3 + 2];
    const float u10 = Wc2[k1 * 3 + 0], u11 = Wc2[k1 * 3 + 1], u12 = Wc2[k1 * 3 + 2];

    float g0 = 0.f, g1 = 0.f, g2 = 0.f;
    #pragma unroll 1
    for (int m = 0; m < 32; ++m) {
        const float qx = __shfl(px, m);
        const float qy = __shfl(py, m);
        const float qz = __shfl(pz, m);
        const float h0 = fmaxf(fmaf(qx, cx0, fmaf(qy, cy0, fmaf(qz, cz0, cb0))), 0.f);
        const float h1 = fmaxf(fmaf(qx, cx1, fmaf(qy, cy1, fmaf(qz, cz1, cb1))), 0.f);
        float a0 = fmaf(h0, u00, h1 * u10);
        float a1 = fmaf(h0, u01, h1 * u11);
        float a2 = fmaf(h0, u02, h1 * u12);
        #pragma unroll
        for (int mask = 1; mask < 64; mask <<= 1) {
            a0 += __shfl_xor(a0, mask);
            a1 += __shfl_xor(a1, mask);
            a2 += __shfl_xor(a2, mask);
        }
        if (lane == m) { g0 = a0; g1 = a1; g2 = a2; }
    }

    if (e == 0 && lane < 32) {
        float c0 = 0.f, c1 = 0.f, c2 = 0.f;
        if (frozen || dist < FAR_D) {
            c0 = 1.0f / (1.0f + __expf(-(g0 + bc2[0])));
            c1 = 1.0f / (1.0f + __expf(-(g1 + bc2[1])));
            c2 = 1.0f / (1.0f + __expf(-(g2 + bc2[2])));
        }
        out[ray * 3 + 0] = c0;
        out[ray * 3 + 1] = c1;
        out[ray * 3 + 2] = c2;
    }
}

extern "C" void kernel_launch(void* const* d_in, const int* in_sizes, int n_in,
                              void* d_out, int out_size, void* d_ws, size_t ws_size,
                              hipStream_t stream) {
    const float* origins    = (const float*)d_in[0];
    const float* directions = (const float*)d_in[1];
    const float* W1  = (const float*)d_in[2];
    const float* b1  = (const float*)d_in[3];
    const float* W2  = (const float*)d_in[4];
    const float* b2  = (const float*)d_in[5];
    const float* W3  = (const float*)d_in[6];
    const float* b3  = (const float*)d_in[7];
    const float* Wc1 = (const float*)d_in[8];
    const float* bc1 = (const float*)d_in[9];
    const float* Wc2 = (const float*)d_in[10];
    const float* bc2 = (const float*)d_in[11];
    float* out = (float*)d_out;

    char* ws = (char*)d_ws;
    _Float16* w2img = (_Float16*)ws;            // 64 KB
    float4*   w1q   = (float4*)(ws + 65536);    // 2 KB, 16B-aligned

    w2_frag_kernel<<<64, 256, 0, stream>>>(W2, W1, b1, w2img, w1q);

    sphere_trace_kernel<<<N_RAYS / 128, 512, 0, stream>>>(
        origins, directions, W1, b1, w1q, w2img, b2, W3, b3,
        Wc1, bc1, Wc2, bc2, out);
}